// Round 10
// baseline (110.819 us; speedup 1.0000x reference)
//
#include <hip/hip_runtime.h>

// DCNv2, fp32 in/out, all matmul-shaped work on bf16 MFMA.
// Round 10: phase-A im2col halo staged in LDS ONCE (3 rows x 66 px x 64ch,
// hi+lo, zero-filled borders), frags read DIRECTLY from the row buffer in
// MFMA layout -> kills the 9x re-fetch of the halo from global (TCP-line
// model validated by R9's A-frag dedup win), the per-kk validity VALU, and
// all 9 phase-A staging barriers. Phase B identical to R9 (wave=cout tile,
// dbuf 1 barrier/kk, cvt_pk pack). LDS pool 50688 B with aliasing:
//   [0,25344) rows_hi | [25344,50688) rows_lo   (phase A only)
//   [0,16384) phase-B dbuf | [16384,20992) offL (written after rows die)
// ws: xThi 8388608 | xTlo 8388608 | wdA 73728 | woAhi 36864 | woAlo 36864

#define BATCH 4
#define CIN   64
#define COUT  64
#define HH    128
#define WW    128
#define HWPIX (HH*WW)
#define ROWS_LO 25344

typedef __attribute__((ext_vector_type(8))) short short8;   // 8 bf16 (4 VGPRs)
typedef __attribute__((ext_vector_type(4))) float floatx4;  // MFMA C/D

__device__ __forceinline__ unsigned short f2bf(float f) {   // RNE f32->bf16
  unsigned int u = __float_as_uint(f);
  unsigned int r = u + 0x7fffu + ((u >> 16) & 1u);
  return (unsigned short)(r >> 16);
}
__device__ __forceinline__ float bf2f(unsigned short h) { return __uint_as_float(((unsigned int)h) << 16); }
__device__ __forceinline__ float lo16f(unsigned int u) { return __uint_as_float(u << 16); }
__device__ __forceinline__ float hi16f(unsigned int u) { return __uint_as_float(u & 0xffff0000u); }

// 2-channel bilinear blend; pack via HW RNE convert (== f2bf pair).
__device__ __forceinline__ unsigned int bilin2(unsigned int u00, unsigned int u01,
                                               unsigned int u10, unsigned int u11,
                                               float w00, float w01, float w10, float w11) {
  float lo = w00 * lo16f(u00) + w01 * lo16f(u01) + w10 * lo16f(u10) + w11 * lo16f(u11);
  float hi = w00 * hi16f(u00) + w01 * hi16f(u01) + w10 * hi16f(u10) + w11 * hi16f(u11);
  unsigned int r;
  asm("v_cvt_pk_bf16_f32 %0, %1, %2" : "=v"(r) : "v"(lo), "v"(hi));
  return r;
}

// dbuf swizzle (phase B staging): fold bits 9-10 into 4-5.
__device__ __forceinline__ int swz(int a) { return a ^ (((a >> 9) & 3) << 4); }
// row-buffer swizzle: fold xi low bits (addr bits 7-9) into bank bits 4-6.
__device__ __forceinline__ int swzR(int a) { return a ^ (((a >> 7) & 7) << 4); }

// Fused preprocessing (unchanged):
__global__ __launch_bounds__(256) void pre_kernel(const float* __restrict__ x,
                                                  const float* __restrict__ wo,
                                                  const float* __restrict__ wd,
                                                  unsigned short* __restrict__ xThi,
                                                  unsigned short* __restrict__ xTlo,
                                                  unsigned short* __restrict__ wdA,
                                                  unsigned short* __restrict__ woAhi,
                                                  unsigned short* __restrict__ woAlo) {
  int tid = threadIdx.x;
  if (blockIdx.x < 4096) {
    __shared__ float tile[32][33];   // [c_local][p_local]
    int t = blockIdx.x;
    int b = t >> 10, rem = t & 1023;
    int c0 = (rem >> 9) * 32, p0 = (rem & 511) * 32;
    int tx = tid & 31, ty = tid >> 5;      // (32,8)
    const float* xb = x + (size_t)b * CIN * HWPIX;
    size_t boff = (size_t)b * HWPIX * CIN;
#pragma unroll
    for (int i = 0; i < 4; i++)
      tile[ty + i * 8][tx] = xb[(size_t)(c0 + ty + i * 8) * HWPIX + p0 + tx];
    __syncthreads();
#pragma unroll
    for (int i = 0; i < 2; i++) {
      int tt = tid + i * 256;       // 0..511 = 32 rows * 16 cin-pairs
      int row = tt >> 4;
      int cp = tt & 15;
      float v0 = tile[cp * 2][row], v1 = tile[cp * 2 + 1][row];
      unsigned short h0 = f2bf(v0), h1 = f2bf(v1);
      unsigned short l0 = f2bf(v0 - bf2f(h0)), l1 = f2bf(v1 - bf2f(h1));
      size_t o = boff + (size_t)(p0 + row) * CIN + c0 + cp * 2;
      *(ushort2*)&xThi[o] = make_ushort2(h0, h1);
      *(ushort2*)&xTlo[o] = make_ushort2(l0, l1);
    }
  } else {
    int t = (blockIdx.x - 4096) * 256 + tid;
    if (t < 36864) {
      int j = t & 7, lane = (t >> 3) & 63, ct = (t >> 9) & 3, kc = (t >> 11) & 1, kk = t >> 12;
      int cout = ct * 16 + (lane & 15);
      int cin  = kc * 32 + (lane >> 4) * 8 + j;
      wdA[t] = f2bf(wd[(size_t)(cout * CIN + cin) * 9 + kk]);
    }
    int t2 = t - 36864;
    if (t2 >= 0 && t2 < 18432) {
      int j = t2 & 7, lane = (t2 >> 3) & 63, ct = (t2 >> 9) & 1, kc = (t2 >> 10) & 1, kk = t2 >> 11;
      int cout = ct * 16 + (lane & 15);          // conv channel 0..31 (valid < 18)
      int cin  = kc * 32 + (lane >> 4) * 8 + j;
      float v = (cout < 18) ? wo[(size_t)(cout * CIN + cin) * 9 + kk] : 0.f;
      unsigned short h = f2bf(v);
      woAhi[t2] = h;
      woAlo[t2] = f2bf(v - bf2f(h));
    }
  }
}

// Fused offset-conv + deform GEMM.
// Block: 64 px tile (b, y, x0..x0+63), 256 thr = 4 waves.
// Phase A: halo rows in LDS, direct frag reads, wave -> (ct=w&1, px pair).
// Phase B: R9 structure (dbuf 1 barrier/kk, wave -> ct=w, px-groups 0..3).
__global__ __launch_bounds__(256) void fused_dcn_kernel(const unsigned short* __restrict__ xThi,
                                                        const unsigned short* __restrict__ xTlo,
                                                        const unsigned short* __restrict__ woAhi,
                                                        const unsigned short* __restrict__ woAlo,
                                                        const unsigned short* __restrict__ wdA,
                                                        float* __restrict__ out) {
  __shared__ char pool[50688];
  float* offL = (float*)(pool + 16384);    // alias: live from phase-A end onward

  int tid = threadIdx.x;
  int hw = blockIdx.x;
  int bid = (hw & 7) * 128 + (hw >> 3);    // XCD-contiguous y bands
  int b = bid >> 8, r = bid & 255, y = r >> 1, x0 = (r & 1) << 6;

  int p1 = tid >> 2, si = tid & 3;
  int lane = tid & 63, w = tid >> 6;
  int colp = lane & 15, g = lane >> 4;

  const unsigned short* xhib = xThi + (size_t)b * HWPIX * CIN;
  const unsigned short* xlob = xTlo + (size_t)b * HWPIX * CIN;

  // ---- stage halo: 3 rows x 66 px x 64 ch, hi+lo, zero-filled borders ----
  // slot t (16B): ri = t/528, xi = (t%528)>>3, sl = t&7; byte addr = t*16.
  for (int t = tid; t < 1584; t += 256) {
    int ri = t / 528;
    int rem = t - ri * 528;
    int xi = rem >> 3, sl = rem & 7;
    int ys = y - 1 + ri, xs = x0 - 1 + xi;
    uint4 vh = {0, 0, 0, 0}, vl = {0, 0, 0, 0};
    if (ys >= 0 && ys < HH && xs >= 0 && xs < WW) {
      const unsigned short* ph = xhib + (size_t)(ys * WW + xs) * CIN + sl * 8;
      const unsigned short* pl = xlob + (size_t)(ys * WW + xs) * CIN + sl * 8;
      vh = *(const uint4*)ph; vl = *(const uint4*)pl;
    }
    int a = t * 16;
    *(uint4*)(pool + swzR(a)) = vh;
    *(uint4*)(pool + ROWS_LO + swzR(a)) = vl;
  }
  __syncthreads();

  // ================= Phase A: offset conv (direct LDS frag reads) ==========
  floatx4 oacc[2];
  oacc[0] = (floatx4){0.f, 0.f, 0.f, 0.f};
  oacc[1] = (floatx4){0.f, 0.f, 0.f, 0.f};
  int ctA = w & 1, pgA = (w >> 1) * 2;

#pragma unroll
  for (int kk = 0; kk < 9; kk++) {
    int kd = kk / 3, km = kk % 3;          // compile-time (loop unrolled)
    const short8* Ah = (const short8*)(woAhi + (size_t)kk * 2048);
    const short8* Al = (const short8*)(woAlo + (size_t)kk * 2048);
    short8 ah0 = Ah[ctA * 64 + lane], ah1 = Ah[128 + ctA * 64 + lane];
    short8 al0 = Al[ctA * 64 + lane], al1 = Al[128 + ctA * 64 + lane];
#pragma unroll
    for (int pgi = 0; pgi < 2; pgi++) {
      int xi = (pgA + pgi) * 16 + colp + km;        // px + km, 0..65
      int ab = (kd * 66 + xi) * 128 + g * 16;       // bh0: ch g*8..g*8+8
      short8 bh0 = *(const short8*)(pool + swzR(ab));
      short8 bh1 = *(const short8*)(pool + swzR(ab + 64));          // ch 32+g*8
      short8 bl0 = *(const short8*)(pool + ROWS_LO + swzR(ab));
      short8 bl1 = *(const short8*)(pool + ROWS_LO + swzR(ab + 64));
      oacc[pgi] = __builtin_amdgcn_mfma_f32_16x16x32_bf16(ah0, bh0, oacc[pgi], 0, 0, 0);
      oacc[pgi] = __builtin_amdgcn_mfma_f32_16x16x32_bf16(ah0, bl0, oacc[pgi], 0, 0, 0);
      oacc[pgi] = __builtin_amdgcn_mfma_f32_16x16x32_bf16(al0, bh0, oacc[pgi], 0, 0, 0);
      oacc[pgi] = __builtin_amdgcn_mfma_f32_16x16x32_bf16(ah1, bh1, oacc[pgi], 0, 0, 0);
      oacc[pgi] = __builtin_amdgcn_mfma_f32_16x16x32_bf16(ah1, bl1, oacc[pgi], 0, 0, 0);
      oacc[pgi] = __builtin_amdgcn_mfma_f32_16x16x32_bf16(al1, bh1, oacc[pgi], 0, 0, 0);
    }
  }

  __syncthreads();   // retire all row reads before offL (aliases rows) is written

  // offL scatter (wave w: rows ctA*16.., cols pgA*16..) then barrier.
  {
    int rowb = (lane >> 4) * 4;
    int colb = pgA * 16 + colp;
#pragma unroll
    for (int pgi = 0; pgi < 2; pgi++)
#pragma unroll
      for (int rr = 0; rr < 4; rr++) {
        int row = ctA * 16 + rowb + rr;
        if (row < 18) offL[row * 64 + colb + pgi * 16] = oacc[pgi][rr];
      }
  }
  __syncthreads();

  // ================= Phase B: deform sample + GEMM (dbuf, wave=ct) =========
  char* sHc = pool;                        // dbuf: 2 x 8192 B, aliases rows_hi
  int wq = p1 >> 4, iq = p1 & 15;
  int kcd = si >> 1, qb = si & 1;
  int wb0 = ((((wq * 2 + kcd) * 64) + qb * 32 + iq) * 8) * 2;
  int wb1 = wb0 + 256;
  int swb0 = swz(wb0), swb1 = swz(wb1);
  int brb0[4], brb1[4];
#pragma unroll
  for (int pg = 0; pg < 4; pg++) {
    brb0[pg] = swz(pg * 2048 + lane * 16);
    brb1[pg] = swz(pg * 2048 + 1024 + lane * 16);
  }
  int xp = x0 + p1;

  floatx4 acc[4];
#pragma unroll
  for (int pg = 0; pg < 4; pg++) acc[pg] = (floatx4){0.f, 0.f, 0.f, 0.f};

  struct BS {
    float w00, w01, w10, w11;
    uint4 a00, a01, a10, a11, b00, b01, b10, b11;
  };
  auto ldB = [&](int kk) -> BS {
    BS s;
    float dy = offL[(2 * kk) * 64 + p1];
    float dx = offL[(2 * kk + 1) * 64 + p1];
    float ys = (float)(y - 1 + kk / 3) + dy;
    float xs = (float)(xp - 1 + kk % 3) + dx;
    float y0f = floorf(ys), x0f = floorf(xs);
    float wy = ys - y0f, wx = xs - x0f;
    int iy0 = (int)y0f, ix0 = (int)x0f;
    int iy1 = iy0 + 1, ix1 = ix0 + 1;
    s.w00 = (1.f - wy) * (1.f - wx); s.w01 = (1.f - wy) * wx;
    s.w10 = wy * (1.f - wx);         s.w11 = wy * wx;
    bool vy0 = (iy0 >= 0) && (iy0 < HH), vy1 = (iy1 >= 0) && (iy1 < HH);
    bool vx0 = (ix0 >= 0) && (ix0 < WW), vx1 = (ix1 >= 0) && (ix1 < WW);
    if (!(vy0 && vx0)) s.w00 = 0.f;
    if (!(vy0 && vx1)) s.w01 = 0.f;
    if (!(vy1 && vx0)) s.w10 = 0.f;
    if (!(vy1 && vx1)) s.w11 = 0.f;
    int cy0 = min(max(iy0, 0), HH - 1), cy1 = min(max(iy1, 0), HH - 1);
    int cx0 = min(max(ix0, 0), WW - 1), cx1 = min(max(ix1, 0), WW - 1);
    const unsigned short* q00 = xhib + (size_t)(cy0 * WW + cx0) * CIN + si * 16;
    const unsigned short* q01 = xhib + (size_t)(cy0 * WW + cx1) * CIN + si * 16;
    const unsigned short* q10 = xhib + (size_t)(cy1 * WW + cx0) * CIN + si * 16;
    const unsigned short* q11 = xhib + (size_t)(cy1 * WW + cx1) * CIN + si * 16;
    s.a00 = *(const uint4*)q00; s.a01 = *(const uint4*)q01;
    s.a10 = *(const uint4*)q10; s.a11 = *(const uint4*)q11;
    s.b00 = *(const uint4*)(q00 + 8); s.b01 = *(const uint4*)(q01 + 8);
    s.b10 = *(const uint4*)(q10 + 8); s.b11 = *(const uint4*)(q11 + 8);
    return s;
  };
  auto blendStoreB = [&](int nxt, const BS& s) {
    uint4 o0, o1;
    o0.x = bilin2(s.a00.x, s.a01.x, s.a10.x, s.a11.x, s.w00, s.w01, s.w10, s.w11);
    o0.y = bilin2(s.a00.y, s.a01.y, s.a10.y, s.a11.y, s.w00, s.w01, s.w10, s.w11);
    o0.z = bilin2(s.a00.z, s.a01.z, s.a10.z, s.a11.z, s.w00, s.w01, s.w10, s.w11);
    o0.w = bilin2(s.a00.w, s.a01.w, s.a10.w, s.a11.w, s.w00, s.w01, s.w10, s.w11);
    o1.x = bilin2(s.b00.x, s.b01.x, s.b10.x, s.b11.x, s.w00, s.w01, s.w10, s.w11);
    o1.y = bilin2(s.b00.y, s.b01.y, s.b10.y, s.b11.y, s.w00, s.w01, s.w10, s.w11);
    o1.z = bilin2(s.b00.z, s.b01.z, s.b10.z, s.b11.z, s.w00, s.w01, s.w10, s.w11);
    o1.w = bilin2(s.b00.w, s.b01.w, s.b10.w, s.b11.w, s.w00, s.w01, s.w10, s.w11);
    *(uint4*)(sHc + nxt * 8192 + swb0) = o0;
    *(uint4*)(sHc + nxt * 8192 + swb1) = o1;
  };
  auto mfmaB = [&](int kk, int cur) {
    const short8* Ap = (const short8*)(wdA + (size_t)kk * 4096);
    short8 a0 = Ap[w * 64 + lane];          // this wave's ct only (A dedup)
    short8 a1 = Ap[256 + w * 64 + lane];
#pragma unroll
    for (int pg = 0; pg < 4; pg++) {
      short8 bv0 = *(const short8*)(sHc + cur * 8192 + brb0[pg]);
      short8 bv1 = *(const short8*)(sHc + cur * 8192 + brb1[pg]);
      acc[pg] = __builtin_amdgcn_mfma_f32_16x16x32_bf16(a0, bv0, acc[pg], 0, 0, 0);
      acc[pg] = __builtin_amdgcn_mfma_f32_16x16x32_bf16(a1, bv1, acc[pg], 0, 0, 0);
    }
  };

  {
    BS s0 = ldB(0);
    blendStoreB(0, s0);
    __syncthreads();
#pragma unroll 1
    for (int kk = 0; kk < 9; kk++) {
      BS sn;
      if (kk < 8) sn = ldB(kk + 1);          // issue gathers early
      mfmaB(kk, kk & 1);                     // consume cur buffer
      if (kk < 8) blendStoreB((kk + 1) & 1, sn);
      __syncthreads();                       // next buf ready / cur free
    }
  }

  // D: col = lane&15 (px within pg tile), row = (lane>>4)*4 + reg;
  // wave w owns couts [16w, 16w+16) for all 4 px-groups.
  int rowb = (lane >> 4) * 4;
  float* outb = out + (size_t)b * COUT * HWPIX + y * WW + x0 + colp;
#pragma unroll
  for (int pg = 0; pg < 4; pg++)
#pragma unroll
    for (int rr = 0; rr < 4; rr++)
      outb[(size_t)(w * 16 + rowb + rr) * HWPIX + pg * 16] = acc[pg][rr];
}

extern "C" void kernel_launch(void* const* d_in, const int* in_sizes, int n_in,
                              void* d_out, int out_size, void* d_ws, size_t ws_size,
                              hipStream_t stream) {
  const float* x  = (const float*)d_in[0];
  const float* wo = (const float*)d_in[1];
  const float* wd = (const float*)d_in[2];
  float* out = (float*)d_out;

  char* wsb = (char*)d_ws;
  unsigned short* xThi  = (unsigned short*)wsb;                         // 8,388,608 B
  unsigned short* xTlo  = (unsigned short*)(wsb + 8388608);             // 8,388,608 B
  unsigned short* wdA   = (unsigned short*)(wsb + 16777216);            // 73,728 B
  unsigned short* woAhi = (unsigned short*)(wsb + 16777216 + 73728);    // 36,864 B
  unsigned short* woAlo = (unsigned short*)(wsb + 16850944 + 36864);    // 36,864 B

  pre_kernel<<<dim3(4096 + 216), dim3(256), 0, stream>>>(x, wo, wd, xThi, xTlo, wdA, woAhi, woAlo);
  fused_dcn_kernel<<<dim3(BATCH * HWPIX / 64), dim3(256), 0, stream>>>(xThi, xTlo, woAhi, woAlo, wdA, out);
}

// Round 11
// 109.556 us; speedup vs baseline: 1.0115x; 1.0115x over previous
//
#include <hip/hip_runtime.h>

// DCNv2, fp32 in/out, all matmul-shaped work on bf16 MFMA.
// Round 11: R9 arithmetic at HALF tile size -> 2x grid (2048 blocks).
// Grid was 1024 on 256 CUs = hard 4-blocks/CU occupancy cap (the hidden
// limiter of R1-R10). Block: 32 px x 64 cout, 256 thr = 4 waves.
// Staging view: p1 = tid>>3 (px 0..31), o = tid&7 (8-ch slice), swzB LDS
// swizzle (R7-verified layout, ~33K conflicts). Phase A: dbuf 1 barrier/kk,
// wave=(ct,pg); phase B: dbuf 1 barrier/kk, wave=ct (A-frag dedup kept),
// pg-loop over 2 px-groups. Per-output MFMA order identical to R9 ->
// bit-identical results. LDS 18688 B -> 8 blocks/CU (grid-limited).
// ws: xThi 8388608 | xTlo 8388608 | wdA 73728 | woAhi 36864 | woAlo 36864

#define BATCH 4
#define CIN   64
#define COUT  64
#define HH    128
#define WW    128
#define HWPIX (HH*WW)

typedef __attribute__((ext_vector_type(8))) short short8;   // 8 bf16 (4 VGPRs)
typedef __attribute__((ext_vector_type(4))) float floatx4;  // MFMA C/D

__device__ __forceinline__ unsigned short f2bf(float f) {   // RNE f32->bf16
  unsigned int u = __float_as_uint(f);
  unsigned int r = u + 0x7fffu + ((u >> 16) & 1u);
  return (unsigned short)(r >> 16);
}
__device__ __forceinline__ float bf2f(unsigned short h) { return __uint_as_float(((unsigned int)h) << 16); }
__device__ __forceinline__ float lo16f(unsigned int u) { return __uint_as_float(u << 16); }
__device__ __forceinline__ float hi16f(unsigned int u) { return __uint_as_float(u & 0xffff0000u); }

// 2-channel bilinear blend; pack via HW RNE convert (== f2bf pair).
__device__ __forceinline__ unsigned int bilin2(unsigned int u00, unsigned int u01,
                                               unsigned int u10, unsigned int u11,
                                               float w00, float w01, float w10, float w11) {
  float lo = w00 * lo16f(u00) + w01 * lo16f(u01) + w10 * lo16f(u10) + w11 * lo16f(u11);
  float hi = w00 * hi16f(u00) + w01 * hi16f(u01) + w10 * hi16f(u10) + w11 * hi16f(u11);
  unsigned int r;
  asm("v_cvt_pk_bf16_f32 %0, %1, %2" : "=v"(r) : "v"(lo), "v"(hi));
  return r;
}

// LDS byte swizzle for 4KB frag buffers: fold bits 8-10 into 4-6
// (bijective involution; R7-verified low-conflict on this layout).
__device__ __forceinline__ int swzB(int a) { return a ^ (((a >> 8) & 7) << 4); }

// Fused preprocessing (unchanged):
//  blocks [0,4096):  x fp32 NCHW -> xThi/xTlo bf16 [b][px][cin]
//  blocks [4096,4312): weight prep
__global__ __launch_bounds__(256) void pre_kernel(const float* __restrict__ x,
                                                  const float* __restrict__ wo,
                                                  const float* __restrict__ wd,
                                                  unsigned short* __restrict__ xThi,
                                                  unsigned short* __restrict__ xTlo,
                                                  unsigned short* __restrict__ wdA,
                                                  unsigned short* __restrict__ woAhi,
                                                  unsigned short* __restrict__ woAlo) {
  int tid = threadIdx.x;
  if (blockIdx.x < 4096) {
    __shared__ float tile[32][33];   // [c_local][p_local]
    int t = blockIdx.x;
    int b = t >> 10, rem = t & 1023;
    int c0 = (rem >> 9) * 32, p0 = (rem & 511) * 32;
    int tx = tid & 31, ty = tid >> 5;      // (32,8)
    const float* xb = x + (size_t)b * CIN * HWPIX;
    size_t boff = (size_t)b * HWPIX * CIN;
#pragma unroll
    for (int i = 0; i < 4; i++)
      tile[ty + i * 8][tx] = xb[(size_t)(c0 + ty + i * 8) * HWPIX + p0 + tx];
    __syncthreads();
#pragma unroll
    for (int i = 0; i < 2; i++) {
      int tt = tid + i * 256;       // 0..511 = 32 rows * 16 cin-pairs
      int row = tt >> 4;
      int cp = tt & 15;
      float v0 = tile[cp * 2][row], v1 = tile[cp * 2 + 1][row];
      unsigned short h0 = f2bf(v0), h1 = f2bf(v1);
      unsigned short l0 = f2bf(v0 - bf2f(h0)), l1 = f2bf(v1 - bf2f(h1));
      size_t o = boff + (size_t)(p0 + row) * CIN + c0 + cp * 2;
      *(ushort2*)&xThi[o] = make_ushort2(h0, h1);
      *(ushort2*)&xTlo[o] = make_ushort2(l0, l1);
    }
  } else {
    int t = (blockIdx.x - 4096) * 256 + tid;
    if (t < 36864) {
      int j = t & 7, lane = (t >> 3) & 63, ct = (t >> 9) & 3, kc = (t >> 11) & 1, kk = t >> 12;
      int cout = ct * 16 + (lane & 15);
      int cin  = kc * 32 + (lane >> 4) * 8 + j;
      wdA[t] = f2bf(wd[(size_t)(cout * CIN + cin) * 9 + kk]);
    }
    int t2 = t - 36864;
    if (t2 >= 0 && t2 < 18432) {
      int j = t2 & 7, lane = (t2 >> 3) & 63, ct = (t2 >> 9) & 1, kc = (t2 >> 10) & 1, kk = t2 >> 11;
      int cout = ct * 16 + (lane & 15);          // conv channel 0..31 (valid < 18)
      int cin  = kc * 32 + (lane >> 4) * 8 + j;
      float v = (cout < 18) ? wo[(size_t)(cout * CIN + cin) * 9 + kk] : 0.f;
      unsigned short h = f2bf(v);
      woAhi[t2] = h;
      woAlo[t2] = f2bf(v - bf2f(h));
    }
  }
}

// Fused offset-conv + deform GEMM; 32-px tiles, dbuf 1 barrier/kk.
// Block: 32 px (b, y, x0..x0+31), 256 thr = 4 waves.
// Staging: p1 = tid>>3 (px), o = tid&7 (8-ch slice).
// Phase A MFMA: wave w -> (ctA = w&1, pgW = w>>1).
// Phase B MFMA: wave w -> ct = w (couts 16w..16w+16), pg-loop 0..1.
__global__ __launch_bounds__(256) void fused_dcn_kernel(const unsigned short* __restrict__ xThi,
                                                        const unsigned short* __restrict__ xTlo,
                                                        const unsigned short* __restrict__ woAhi,
                                                        const unsigned short* __restrict__ woAlo,
                                                        const unsigned short* __restrict__ wdA,
                                                        float* __restrict__ out) {
  __shared__ unsigned short sBhi2[2][2048];   // 8 KB; A: im2col hi dbuf; B: sampled dbuf
  __shared__ unsigned short sBlo2[2][2048];   // 8 KB; A only: im2col lo dbuf
  __shared__ float offL[18 * 32];             // 2.25 KB
  char* sHc = (char*)sBhi2;
  char* sLc = (char*)sBlo2;

  int tid = threadIdx.x;
  int hw = blockIdx.x;
  int bid = (hw & 7) * 256 + (hw >> 3);    // XCD-contiguous bands (2048%8==0)
  int b = bid >> 9, r = bid & 511, y = r >> 2, x0 = (r & 3) << 5;

  int p1 = tid >> 3, o = tid & 7;
  int lane = tid & 63, w = tid >> 6;
  int colp = lane & 15;

  const unsigned short* xhib = xThi + (size_t)b * HWPIX * CIN;
  const unsigned short* xlob = xTlo + (size_t)b * HWPIX * CIN;

  // staging byte offset (within one 4KB buffer), swizzled once
  int pgS = p1 >> 4, iq = p1 & 15, kcS = o >> 2, gS = o & 3;
  int sab = swzB(pgS * 2048 + kcS * 1024 + gS * 256 + iq * 16);
  // read offsets per (pg, kc)
  int rAB[2][2];
#pragma unroll
  for (int pg = 0; pg < 2; pg++)
#pragma unroll
    for (int kc = 0; kc < 2; kc++)
      rAB[pg][kc] = swzB(pg * 2048 + kc * 1024 + lane * 16);

  int xp = x0 + p1;

  // ================= Phase A: offset conv (dbuf, 1 barrier/kk) =============
  floatx4 oaccA = (floatx4){0.f, 0.f, 0.f, 0.f};
  int ctA = w & 1, pgW = w >> 1;

  auto ldA = [&](int kk, uint4& h, uint4& l) {
    int ys = y - 1 + kk / 3;
    int xs = xp - 1 + kk % 3;
    bool valid = (ys >= 0) && (ys < HH) && (xs >= 0) && (xs < WW);
    h = (uint4){0, 0, 0, 0}; l = h;
    if (valid) {
      h = *(const uint4*)(xhib + (size_t)(ys * WW + xs) * CIN + o * 8);
      l = *(const uint4*)(xlob + (size_t)(ys * WW + xs) * CIN + o * 8);
    }
  };
  auto stageA = [&](int nxt, const uint4& h, const uint4& l) {
    *(uint4*)(sHc + nxt * 4096 + sab) = h;
    *(uint4*)(sLc + nxt * 4096 + sab) = l;
  };
  auto mfmaA = [&](int kk, int cur) {
    const short8* Ah = (const short8*)(woAhi + (size_t)kk * 2048);
    const short8* Al = (const short8*)(woAlo + (size_t)kk * 2048);
    short8 ah0 = Ah[ctA * 64 + lane], ah1 = Ah[128 + ctA * 64 + lane];
    short8 al0 = Al[ctA * 64 + lane], al1 = Al[128 + ctA * 64 + lane];
    short8 bh0 = *(const short8*)(sHc + cur * 4096 + rAB[pgW][0]);
    short8 bh1 = *(const short8*)(sHc + cur * 4096 + rAB[pgW][1]);
    short8 bl0 = *(const short8*)(sLc + cur * 4096 + rAB[pgW][0]);
    short8 bl1 = *(const short8*)(sLc + cur * 4096 + rAB[pgW][1]);
    oaccA = __builtin_amdgcn_mfma_f32_16x16x32_bf16(ah0, bh0, oaccA, 0, 0, 0);
    oaccA = __builtin_amdgcn_mfma_f32_16x16x32_bf16(ah0, bl0, oaccA, 0, 0, 0);
    oaccA = __builtin_amdgcn_mfma_f32_16x16x32_bf16(al0, bh0, oaccA, 0, 0, 0);
    oaccA = __builtin_amdgcn_mfma_f32_16x16x32_bf16(ah1, bh1, oaccA, 0, 0, 0);
    oaccA = __builtin_amdgcn_mfma_f32_16x16x32_bf16(ah1, bl1, oaccA, 0, 0, 0);
    oaccA = __builtin_amdgcn_mfma_f32_16x16x32_bf16(al1, bh1, oaccA, 0, 0, 0);
  };

  {
    uint4 hc, lc;
    ldA(0, hc, lc);
    stageA(0, hc, lc);
    __syncthreads();
#pragma unroll 1
    for (int kk = 0; kk < 9; kk++) {
      uint4 hn, ln;
      if (kk < 8) ldA(kk + 1, hn, ln);     // issue gathers early
      mfmaA(kk, kk & 1);                   // consume cur buffer
      if (kk < 8) stageA((kk + 1) & 1, hn, ln);
      __syncthreads();                     // next buf ready / cur free
    }
  }

  // offL scatter: wave w -> rows ctA*16.., cols pgW*16.. ; barrier (cross-wave).
  {
    int rowb = (lane >> 4) * 4;
#pragma unroll
    for (int rr = 0; rr < 4; rr++) {
      int row = ctA * 16 + rowb + rr;
      if (row < 18) offL[row * 32 + pgW * 16 + colp] = oaccA[rr];
    }
  }
  __syncthreads();

  // ================= Phase B: deform sample + GEMM (dbuf, wave=ct) =========
  floatx4 acc[2];
  acc[0] = (floatx4){0.f, 0.f, 0.f, 0.f};
  acc[1] = (floatx4){0.f, 0.f, 0.f, 0.f};

  struct BS {
    float w00, w01, w10, w11;
    uint4 a00, a01, a10, a11;
  };
  auto ldB = [&](int kk) -> BS {
    BS s;
    float dy = offL[(2 * kk) * 32 + p1];
    float dx = offL[(2 * kk + 1) * 32 + p1];
    float ys = (float)(y - 1 + kk / 3) + dy;
    float xs = (float)(xp - 1 + kk % 3) + dx;
    float y0f = floorf(ys), x0f = floorf(xs);
    float wy = ys - y0f, wx = xs - x0f;
    int iy0 = (int)y0f, ix0 = (int)x0f;
    int iy1 = iy0 + 1, ix1 = ix0 + 1;
    s.w00 = (1.f - wy) * (1.f - wx); s.w01 = (1.f - wy) * wx;
    s.w10 = wy * (1.f - wx);         s.w11 = wy * wx;
    bool vy0 = (iy0 >= 0) && (iy0 < HH), vy1 = (iy1 >= 0) && (iy1 < HH);
    bool vx0 = (ix0 >= 0) && (ix0 < WW), vx1 = (ix1 >= 0) && (ix1 < WW);
    if (!(vy0 && vx0)) s.w00 = 0.f;
    if (!(vy0 && vx1)) s.w01 = 0.f;
    if (!(vy1 && vx0)) s.w10 = 0.f;
    if (!(vy1 && vx1)) s.w11 = 0.f;
    int cy0 = min(max(iy0, 0), HH - 1), cy1 = min(max(iy1, 0), HH - 1);
    int cx0 = min(max(ix0, 0), WW - 1), cx1 = min(max(ix1, 0), WW - 1);
    s.a00 = *(const uint4*)(xhib + (size_t)(cy0 * WW + cx0) * CIN + o * 8);
    s.a01 = *(const uint4*)(xhib + (size_t)(cy0 * WW + cx1) * CIN + o * 8);
    s.a10 = *(const uint4*)(xhib + (size_t)(cy1 * WW + cx0) * CIN + o * 8);
    s.a11 = *(const uint4*)(xhib + (size_t)(cy1 * WW + cx1) * CIN + o * 8);
    return s;
  };
  auto blendStoreB = [&](int nxt, const BS& s) {
    uint4 o0;
    o0.x = bilin2(s.a00.x, s.a01.x, s.a10.x, s.a11.x, s.w00, s.w01, s.w10, s.w11);
    o0.y = bilin2(s.a00.y, s.a01.y, s.a10.y, s.a11.y, s.w00, s.w01, s.w10, s.w11);
    o0.z = bilin2(s.a00.z, s.a01.z, s.a10.z, s.a11.z, s.w00, s.w01, s.w10, s.w11);
    o0.w = bilin2(s.a00.w, s.a01.w, s.a10.w, s.a11.w, s.w00, s.w01, s.w10, s.w11);
    *(uint4*)(sHc + nxt * 4096 + sab) = o0;
  };
  auto mfmaB = [&](int kk, int cur) {
    const short8* Ap = (const short8*)(wdA + (size_t)kk * 4096);
    short8 a0 = Ap[w * 64 + lane];          // this wave's ct only (A dedup)
    short8 a1 = Ap[256 + w * 64 + lane];
#pragma unroll
    for (int pg = 0; pg < 2; pg++) {
      short8 bv0 = *(const short8*)(sHc + cur * 4096 + rAB[pg][0]);
      short8 bv1 = *(const short8*)(sHc + cur * 4096 + rAB[pg][1]);
      acc[pg] = __builtin_amdgcn_mfma_f32_16x16x32_bf16(a0, bv0, acc[pg], 0, 0, 0);
      acc[pg] = __builtin_amdgcn_mfma_f32_16x16x32_bf16(a1, bv1, acc[pg], 0, 0, 0);
    }
  };

  {
    BS s0 = ldB(0);
    blendStoreB(0, s0);
    __syncthreads();
#pragma unroll 1
    for (int kk = 0; kk < 9; kk++) {
      BS sn;
      if (kk < 8) sn = ldB(kk + 1);          // issue gathers early
      mfmaB(kk, kk & 1);                     // consume cur buffer
      if (kk < 8) blendStoreB((kk + 1) & 1, sn);
      __syncthreads();                       // next buf ready / cur free
    }
  }

  // D: col = lane&15 (px within pg tile), row = (lane>>4)*4 + reg;
  // wave w owns couts [16w, 16w+16) for both px-groups.
  int rowb = (lane >> 4) * 4;
  float* outb = out + (size_t)b * COUT * HWPIX + y * WW + x0 + colp;
#pragma unroll
  for (int pg = 0; pg < 2; pg++)
#pragma unroll
    for (int rr = 0; rr < 4; rr++)
      outb[(size_t)(w * 16 + rowb + rr) * HWPIX + pg * 16] = acc[pg][rr];
}

extern "C" void kernel_launch(void* const* d_in, const int* in_sizes, int n_in,
                              void* d_out, int out_size, void* d_ws, size_t ws_size,
                              hipStream_t stream) {
  const float* x  = (const float*)d_in[0];
  const float* wo = (const float*)d_in[1];
  const float* wd = (const float*)d_in[2];
  float* out = (float*)d_out;

  char* wsb = (char*)d_ws;
  unsigned short* xThi  = (unsigned short*)wsb;                         // 8,388,608 B
  unsigned short* xTlo  = (unsigned short*)(wsb + 8388608);             // 8,388,608 B
  unsigned short* wdA   = (unsigned short*)(wsb + 16777216);            // 73,728 B
  unsigned short* woAhi = (unsigned short*)(wsb + 16777216 + 73728);    // 36,864 B
  unsigned short* woAlo = (unsigned short*)(wsb + 16850944 + 36864);    // 36,864 B

  pre_kernel<<<dim3(4096 + 216), dim3(256), 0, stream>>>(x, wo, wd, xThi, xTlo, wdA, woAhi, woAlo);
  fused_dcn_kernel<<<dim3(2048), dim3(256), 0, stream>>>(xThi, xTlo, woAhi, woAlo, wdA, out);
}